// Round 2
// baseline (946.792 us; speedup 1.0000x reference)
//
#include <hip/hip_runtime.h>

// Problem constants (B=4, S=2048 -> T=8192)
#define T_TOKENS 8192
#define H_DIM 1024
#define F_DIM 4096
#define E_NUM 8

typedef unsigned short u16;
typedef __attribute__((ext_vector_type(8))) short bf16x8;
typedef __attribute__((ext_vector_type(4))) float f32x4;

__device__ __forceinline__ u16 f2bf(float f) {
  union { float f; unsigned int u; } v; v.f = f;
  unsigned int r = v.u + 0x7fffu + ((v.u >> 16) & 1u);
  return (u16)(r >> 16);
}

#define GLOAD_LDS(g, l)                                                        \
  __builtin_amdgcn_global_load_lds(                                            \
      (const __attribute__((address_space(1))) void*)(g),                      \
      (__attribute__((address_space(3))) void*)(l), 16, 0, 0)

// ---------------- fp32 -> bf16 convert (vectorized) ----------------
__global__ void cvt_kernel(const float* __restrict__ in, u16* __restrict__ out,
                           int n4) {
  int i = blockIdx.x * blockDim.x + threadIdx.x;
  int stride = gridDim.x * blockDim.x;
  for (; i < n4; i += stride) {
    float4 v = ((const float4*)in)[i];
    ushort4 o;
    o.x = f2bf(v.x); o.y = f2bf(v.y); o.z = f2bf(v.z); o.w = f2bf(v.w);
    ((ushort4*)out)[i] = o;
  }
}

// ------- router: logits + softmax + top2 + renorm, fused x->bf16 cvt -------
__global__ void router_kernel(const float* __restrict__ x,
                              const float* __restrict__ gw,
                              u16* __restrict__ xb,
                              float* __restrict__ logits_out,
                              int* __restrict__ sel, float* __restrict__ selw) {
  int wid = threadIdx.x >> 6;
  int lane = threadIdx.x & 63;
  int t = blockIdx.x * 4 + wid;
  const float4* xr = (const float4*)(x + (size_t)t * H_DIM);
  ushort4* xbr = (ushort4*)(xb + (size_t)t * H_DIM);
  float acc[E_NUM];
#pragma unroll
  for (int e = 0; e < E_NUM; e++) acc[e] = 0.f;
#pragma unroll
  for (int it = 0; it < H_DIM / 256; it++) {
    int i4 = it * 64 + lane;
    float4 v = xr[i4];
    ushort4 o;
    o.x = f2bf(v.x); o.y = f2bf(v.y); o.z = f2bf(v.z); o.w = f2bf(v.w);
    xbr[i4] = o;
#pragma unroll
    for (int e = 0; e < E_NUM; e++) {
      float4 g = ((const float4*)(gw + (size_t)e * H_DIM))[i4];
      acc[e] += v.x * g.x + v.y * g.y + v.z * g.z + v.w * g.w;
    }
  }
#pragma unroll
  for (int off = 32; off > 0; off >>= 1) {
#pragma unroll
    for (int e = 0; e < E_NUM; e++) acc[e] += __shfl_xor(acc[e], off);
  }
  if (lane < E_NUM) logits_out[(size_t)t * E_NUM + lane] = acc[lane];
  if (lane == 0) {
    float m = acc[0];
#pragma unroll
    for (int e = 1; e < E_NUM; e++) m = fmaxf(m, acc[e]);
    float p[E_NUM];
#pragma unroll
    for (int e = 0; e < E_NUM; e++) p[e] = expf(acc[e] - m);
    int e0 = 0; float p0 = p[0];
#pragma unroll
    for (int e = 1; e < E_NUM; e++) if (p[e] > p0) { p0 = p[e]; e0 = e; }
    int e1 = -1; float p1 = -1.f;
#pragma unroll
    for (int e = 0; e < E_NUM; e++)
      if (e != e0 && p[e] > p1) { p1 = p[e]; e1 = e; }
    float inv = 1.f / (p0 + p1);  // softmax denom cancels in renorm
    sel[t * 2] = e0; sel[t * 2 + 1] = e1;
    selw[t * 2] = p0 * inv; selw[t * 2 + 1] = p1 * inv;
  }
}

// ---------------- scatter: build per-expert pair lists ----------------
__global__ void scatter_kernel(const int* __restrict__ sel,
                               const float* __restrict__ selw,
                               int* __restrict__ cnt, int* __restrict__ list,
                               float* __restrict__ wpair) {
  int t = blockIdx.x * blockDim.x + threadIdx.x;
  if (t >= T_TOKENS) return;
#pragma unroll
  for (int k = 0; k < 2; k++) {
    int e = sel[t * 2 + k];
    int pos = atomicAdd(&cnt[e], 1);
    list[e * T_TOKENS + pos] = t * 2 + k;
    wpair[t * 2 + k] = selw[t * 2 + k];
  }
}

// ---- GEMM1: inter = silu(x@w1^T) * (x@w3^T), bf16 out ----
// 256(tokens) x 128(F) tile, BK=64, 512 thr / 8 waves (4M x 2N),
// XOR-swizzled LDS (swizzle on global source; linear global_load_lds dest).
__global__ __launch_bounds__(512, 2) void gemm1_kernel(
    const u16* __restrict__ xb, const u16* __restrict__ w1b,
    const u16* __restrict__ w3b, const int* __restrict__ cnt,
    const int* __restrict__ list, u16* __restrict__ inter) {
  int e = blockIdx.z;
  int ne = cnt[e];
  int m0 = blockIdx.y * 256;
  if (m0 >= ne) return;
  int nb = blockIdx.x;  // F / 128

  __shared__ u16 al[256 * 64];
  __shared__ u16 b1l[128 * 64];
  __shared__ u16 b3l[128 * 64];
  __shared__ int s_pair[256];

  int tid = threadIdx.x;
  if (tid < 256) {
    int idx = m0 + tid;
    s_pair[tid] = list[e * T_TOKENS + (idx < ne ? idx : 0)];
  }
  __syncthreads();

  // staging sources: thread covers (row = r*64 + tid>>3, 16B slot = tid&7),
  // source column swizzled by row&7 so linear LDS dest ends up XOR-swizzled
  int sc = (((tid & 7) ^ ((tid >> 3) & 7)) << 3);
  const u16 *ab[4], *b1b[2], *b3b[2];
#pragma unroll
  for (int r = 0; r < 4; r++) {
    int row = r * 64 + (tid >> 3);
    ab[r] = xb + (size_t)(s_pair[row] >> 1) * H_DIM + sc;
  }
#pragma unroll
  for (int r = 0; r < 2; r++) {
    int row = r * 64 + (tid >> 3);
    b1b[r] = w1b + ((size_t)e * F_DIM + (size_t)nb * 128 + row) * H_DIM + sc;
    b3b[r] = w3b + ((size_t)e * F_DIM + (size_t)nb * 128 + row) * H_DIM + sc;
  }

  int lane = tid & 63;
  int wm = ((tid >> 7) & 3) * 64;  // wave M offset (4 waves along M)
  int wn = ((tid >> 6) & 1) * 64;  // wave N offset (2 waves along N)
  f32x4 zero = {0.f, 0.f, 0.f, 0.f};
  f32x4 acc1[4][4], acc3[4][4];
#pragma unroll
  for (int i = 0; i < 4; i++)
#pragma unroll
    for (int j = 0; j < 4; j++) { acc1[i][j] = zero; acc3[i][j] = zero; }

  for (int kt = 0; kt < H_DIM; kt += 64) {
#pragma unroll
    for (int r = 0; r < 4; r++) GLOAD_LDS(ab[r] + kt, &al[(r * 512 + tid) * 8]);
#pragma unroll
    for (int r = 0; r < 2; r++) {
      GLOAD_LDS(b1b[r] + kt, &b1l[(r * 512 + tid) * 8]);
      GLOAD_LDS(b3b[r] + kt, &b3l[(r * 512 + tid) * 8]);
    }
    __syncthreads();
#pragma unroll
    for (int kk = 0; kk < 2; kk++) {
      int q = kk * 4 + (lane >> 4);
      bf16x8 af[4], bf1[4], bf3[4];
#pragma unroll
      for (int i = 0; i < 4; i++) {
        int row = wm + i * 16 + (lane & 15);
        af[i] = *(const bf16x8*)&al[row * 64 + ((q ^ (row & 7)) << 3)];
      }
#pragma unroll
      for (int j = 0; j < 4; j++) {
        int row = wn + j * 16 + (lane & 15);
        int off = row * 64 + ((q ^ (row & 7)) << 3);
        bf1[j] = *(const bf16x8*)&b1l[off];
        bf3[j] = *(const bf16x8*)&b3l[off];
      }
#pragma unroll
      for (int i = 0; i < 4; i++)
#pragma unroll
        for (int j = 0; j < 4; j++) {
          acc1[i][j] = __builtin_amdgcn_mfma_f32_16x16x32_bf16(
              af[i], bf1[j], acc1[i][j], 0, 0, 0);
          acc3[i][j] = __builtin_amdgcn_mfma_f32_16x16x32_bf16(
              af[i], bf3[j], acc3[i][j], 0, 0, 0);
        }
    }
    __syncthreads();
  }

  // epilogue: SwiGLU, write inter rows (scattered by pair id)
#pragma unroll
  for (int i = 0; i < 4; i++) {
#pragma unroll
    for (int r = 0; r < 4; r++) {
      int ml = wm + i * 16 + (lane >> 4) * 4 + r;
      if (m0 + ml < ne) {
        size_t base =
            (size_t)s_pair[ml] * F_DIM + (size_t)nb * 128 + wn + (lane & 15);
#pragma unroll
        for (int j = 0; j < 4; j++) {
          float h1 = acc1[i][j][r], h3 = acc3[i][j][r];
          float v = h1 / (1.f + __expf(-h1)) * h3;
          inter[base + j * 16] = f2bf(v);
        }
      }
    }
  }
}

// ---- GEMM2: out += w * (inter @ w2^T) ----
// 256(pairs) x 128(H) tile, BK=64, 512 thr / 8 waves (4M x 2N).
__global__ __launch_bounds__(512, 2) void gemm2_kernel(
    const u16* __restrict__ inter, const u16* __restrict__ w2b,
    const int* __restrict__ cnt, const int* __restrict__ list,
    const float* __restrict__ wpair, float* __restrict__ out) {
  int e = blockIdx.z;
  int ne = cnt[e];
  int m0 = blockIdx.y * 256;
  if (m0 >= ne) return;
  int nb = blockIdx.x;  // H / 128

  __shared__ u16 al[256 * 64];
  __shared__ u16 bl[128 * 64];
  __shared__ int s_pair[256];
  __shared__ float s_w[256];

  int tid = threadIdx.x;
  if (tid < 256) {
    int idx = m0 + tid;
    int pr = list[e * T_TOKENS + (idx < ne ? idx : 0)];
    s_pair[tid] = pr;
    s_w[tid] = wpair[pr];
  }
  __syncthreads();

  int sc = (((tid & 7) ^ ((tid >> 3) & 7)) << 3);
  const u16 *ab[4], *bb[2];
#pragma unroll
  for (int r = 0; r < 4; r++) {
    int row = r * 64 + (tid >> 3);
    ab[r] = inter + (size_t)s_pair[row] * F_DIM + sc;
  }
#pragma unroll
  for (int r = 0; r < 2; r++) {
    int row = r * 64 + (tid >> 3);
    bb[r] = w2b + ((size_t)e * H_DIM + (size_t)nb * 128 + row) * F_DIM + sc;
  }

  int lane = tid & 63;
  int wm = ((tid >> 7) & 3) * 64;
  int wn = ((tid >> 6) & 1) * 64;
  f32x4 zero = {0.f, 0.f, 0.f, 0.f};
  f32x4 acc[4][4];
#pragma unroll
  for (int i = 0; i < 4; i++)
#pragma unroll
    for (int j = 0; j < 4; j++) acc[i][j] = zero;

  for (int kt = 0; kt < F_DIM; kt += 64) {
#pragma unroll
    for (int r = 0; r < 4; r++) GLOAD_LDS(ab[r] + kt, &al[(r * 512 + tid) * 8]);
#pragma unroll
    for (int r = 0; r < 2; r++) GLOAD_LDS(bb[r] + kt, &bl[(r * 512 + tid) * 8]);
    __syncthreads();
#pragma unroll
    for (int kk = 0; kk < 2; kk++) {
      int q = kk * 4 + (lane >> 4);
      bf16x8 af[4], bf[4];
#pragma unroll
      for (int i = 0; i < 4; i++) {
        int row = wm + i * 16 + (lane & 15);
        af[i] = *(const bf16x8*)&al[row * 64 + ((q ^ (row & 7)) << 3)];
      }
#pragma unroll
      for (int j = 0; j < 4; j++) {
        int row = wn + j * 16 + (lane & 15);
        bf[j] = *(const bf16x8*)&bl[row * 64 + ((q ^ (row & 7)) << 3)];
      }
#pragma unroll
      for (int i = 0; i < 4; i++)
#pragma unroll
        for (int j = 0; j < 4; j++)
          acc[i][j] = __builtin_amdgcn_mfma_f32_16x16x32_bf16(
              af[i], bf[j], acc[i][j], 0, 0, 0);
    }
    __syncthreads();
  }

  // epilogue: scale by routing weight, atomicAdd into out (2 adds/elem,
  // commutative fp32 -> deterministic)
#pragma unroll
  for (int i = 0; i < 4; i++) {
#pragma unroll
    for (int r = 0; r < 4; r++) {
      int ml = wm + i * 16 + (lane >> 4) * 4 + r;
      if (m0 + ml < ne) {
        int pr = s_pair[ml];
        float w = s_w[ml];
        float* ob =
            out + (size_t)(pr >> 1) * H_DIM + (size_t)nb * 128 + wn + (lane & 15);
#pragma unroll
        for (int j = 0; j < 4; j++) atomicAdd(ob + j * 16, acc[i][j][r] * w);
      }
    }
  }
}

// ---------------- workspace layout (bytes) ----------------
#define XB_OFF 0UL
#define W1B_OFF (XB_OFF + (size_t)T_TOKENS * H_DIM * 2)          // 16 MiB
#define W3B_OFF (W1B_OFF + (size_t)E_NUM * F_DIM * H_DIM * 2)    // +64 MiB
#define W2B_OFF (W3B_OFF + (size_t)E_NUM * F_DIM * H_DIM * 2)
#define INTER_OFF (W2B_OFF + (size_t)E_NUM * F_DIM * H_DIM * 2)
#define CNT_OFF (INTER_OFF + (size_t)2 * T_TOKENS * F_DIM * 2)   // +128 MiB
#define LIST_OFF (CNT_OFF + 256)
#define WPAIR_OFF (LIST_OFF + (size_t)E_NUM * T_TOKENS * 4)
#define SEL_OFF (WPAIR_OFF + (size_t)2 * T_TOKENS * 4)
#define SELW_OFF (SEL_OFF + (size_t)2 * T_TOKENS * 4)

extern "C" void kernel_launch(void* const* d_in, const int* in_sizes, int n_in,
                              void* d_out, int out_size, void* d_ws,
                              size_t ws_size, hipStream_t stream) {
  const float* x = (const float*)d_in[0];
  const float* gw = (const float*)d_in[1];
  const float* w1 = (const float*)d_in[2];
  const float* w2 = (const float*)d_in[3];
  const float* w3 = (const float*)d_in[4];
  float* out = (float*)d_out;
  float* logits_out = out + (size_t)T_TOKENS * H_DIM;

  char* ws = (char*)d_ws;
  u16* xb = (u16*)(ws + XB_OFF);
  u16* w1b = (u16*)(ws + W1B_OFF);
  u16* w3b = (u16*)(ws + W3B_OFF);
  u16* w2b = (u16*)(ws + W2B_OFF);
  u16* inter = (u16*)(ws + INTER_OFF);
  int* cnt = (int*)(ws + CNT_OFF);
  int* list = (int*)(ws + LIST_OFF);
  float* wpair = (float*)(ws + WPAIR_OFF);
  int* sel = (int*)(ws + SEL_OFF);
  float* selw = (float*)(ws + SELW_OFF);

  hipMemsetAsync(d_out, 0, (size_t)T_TOKENS * H_DIM * sizeof(float), stream);
  hipMemsetAsync(cnt, 0, 256, stream);

  cvt_kernel<<<2048, 256, 0, stream>>>(w1, w1b, E_NUM * F_DIM * H_DIM / 4);
  cvt_kernel<<<2048, 256, 0, stream>>>(w3, w3b, E_NUM * F_DIM * H_DIM / 4);
  cvt_kernel<<<2048, 256, 0, stream>>>(w2, w2b, E_NUM * F_DIM * H_DIM / 4);

  router_kernel<<<T_TOKENS / 4, 256, 0, stream>>>(x, gw, xb, logits_out, sel,
                                                  selw);
  scatter_kernel<<<T_TOKENS / 256, 256, 0, stream>>>(sel, selw, cnt, list,
                                                     wpair);

  gemm1_kernel<<<dim3(F_DIM / 128, T_TOKENS / 256, E_NUM), 512, 0, stream>>>(
      xb, w1b, w3b, cnt, list, inter);
  gemm2_kernel<<<dim3(H_DIM / 128, T_TOKENS / 256, E_NUM), 512, 0, stream>>>(
      inter, w2b, cnt, list, wpair, out);
}

// Round 3
// 817.886 us; speedup vs baseline: 1.1576x; 1.1576x over previous
//
#include <hip/hip_runtime.h>

// Problem constants (B=4, S=2048 -> T=8192)
#define T_TOKENS 8192
#define H_DIM 1024
#define F_DIM 4096
#define E_NUM 8

typedef unsigned short u16;
typedef __attribute__((ext_vector_type(8))) short bf16x8;
typedef __attribute__((ext_vector_type(4))) float f32x4;

__device__ __forceinline__ u16 f2bf(float f) {
  union { float f; unsigned int u; } v; v.f = f;
  unsigned int r = v.u + 0x7fffu + ((v.u >> 16) & 1u);
  return (u16)(r >> 16);
}

#define GLOAD_LDS(g, l)                                                        \
  __builtin_amdgcn_global_load_lds(                                            \
      (const __attribute__((address_space(1))) void*)(g),                      \
      (__attribute__((address_space(3))) void*)(l), 16, 0, 0)

// ---------------- fp32 -> bf16 convert (vectorized) ----------------
__global__ void cvt_kernel(const float* __restrict__ in, u16* __restrict__ out,
                           int n4) {
  int i = blockIdx.x * blockDim.x + threadIdx.x;
  int stride = gridDim.x * blockDim.x;
  for (; i < n4; i += stride) {
    float4 v = ((const float4*)in)[i];
    ushort4 o;
    o.x = f2bf(v.x); o.y = f2bf(v.y); o.z = f2bf(v.z); o.w = f2bf(v.w);
    ((ushort4*)out)[i] = o;
  }
}

// ------- router: logits + softmax + top2 + renorm, fused x->bf16 cvt -------
__global__ void router_kernel(const float* __restrict__ x,
                              const float* __restrict__ gw,
                              u16* __restrict__ xb,
                              float* __restrict__ logits_out,
                              int* __restrict__ sel, float* __restrict__ selw) {
  int wid = threadIdx.x >> 6;
  int lane = threadIdx.x & 63;
  int t = blockIdx.x * 4 + wid;
  const float4* xr = (const float4*)(x + (size_t)t * H_DIM);
  ushort4* xbr = (ushort4*)(xb + (size_t)t * H_DIM);
  float acc[E_NUM];
#pragma unroll
  for (int e = 0; e < E_NUM; e++) acc[e] = 0.f;
#pragma unroll
  for (int it = 0; it < H_DIM / 256; it++) {
    int i4 = it * 64 + lane;
    float4 v = xr[i4];
    ushort4 o;
    o.x = f2bf(v.x); o.y = f2bf(v.y); o.z = f2bf(v.z); o.w = f2bf(v.w);
    xbr[i4] = o;
#pragma unroll
    for (int e = 0; e < E_NUM; e++) {
      float4 g = ((const float4*)(gw + (size_t)e * H_DIM))[i4];
      acc[e] += v.x * g.x + v.y * g.y + v.z * g.z + v.w * g.w;
    }
  }
#pragma unroll
  for (int off = 32; off > 0; off >>= 1) {
#pragma unroll
    for (int e = 0; e < E_NUM; e++) acc[e] += __shfl_xor(acc[e], off);
  }
  if (lane < E_NUM) logits_out[(size_t)t * E_NUM + lane] = acc[lane];
  if (lane == 0) {
    float m = acc[0];
#pragma unroll
    for (int e = 1; e < E_NUM; e++) m = fmaxf(m, acc[e]);
    float p[E_NUM];
#pragma unroll
    for (int e = 0; e < E_NUM; e++) p[e] = expf(acc[e] - m);
    int e0 = 0; float p0 = p[0];
#pragma unroll
    for (int e = 1; e < E_NUM; e++) if (p[e] > p0) { p0 = p[e]; e0 = e; }
    int e1 = -1; float p1 = -1.f;
#pragma unroll
    for (int e = 0; e < E_NUM; e++)
      if (e != e0 && p[e] > p1) { p1 = p[e]; e1 = e; }
    float inv = 1.f / (p0 + p1);
    sel[t * 2] = e0; sel[t * 2 + 1] = e1;
    selw[t * 2] = p0 * inv; selw[t * 2 + 1] = p1 * inv;
  }
}

// ---------------- scatter: build per-expert pair lists ----------------
__global__ void scatter_kernel(const int* __restrict__ sel,
                               const float* __restrict__ selw,
                               int* __restrict__ cnt, int* __restrict__ list,
                               float* __restrict__ wpair) {
  int t = blockIdx.x * blockDim.x + threadIdx.x;
  if (t >= T_TOKENS) return;
#pragma unroll
  for (int k = 0; k < 2; k++) {
    int e = sel[t * 2 + k];
    int pos = atomicAdd(&cnt[e], 1);
    list[e * T_TOKENS + pos] = t * 2 + k;
    wpair[t * 2 + k] = selw[t * 2 + k];
  }
}

// ---- Shared 8-phase grouped-GEMM template ----
// Tile: 256(M) x (2 groups x 128)(N), BK=64, 512 thr / 8 waves (4M x 2N).
// G1: A=xb (token rows), B0=w1, B1=w3, K=H, epilogue SwiGLU -> inter (bf16).
// G2: A=inter (pair rows), B0=B1=w2 (col groups), K=F, epilogue atomicAdd out.
// Double-buffered LDS (130 KB, 1 block/CU); counted vmcnt(2) gates (T4);
// raw s_barrier phases (T3); setprio around MFMA clusters (T5).
template <bool G1>
__global__ __launch_bounds__(512, 2) void moe_gemm_kernel(
    const u16* __restrict__ Asrc, const u16* __restrict__ B0src,
    const u16* __restrict__ B1src, const int* __restrict__ cnt,
    const int* __restrict__ list, const float* __restrict__ wpair,
    u16* __restrict__ inter, float* __restrict__ out) {
  constexpr int K = G1 ? H_DIM : F_DIM;   // reduction dim
  constexpr int NT = K / 64;              // K-tiles
  constexpr int BR = G1 ? F_DIM : H_DIM;  // B tensor rows per expert

  int e = blockIdx.z;
  int ne = cnt[e];
  int m0 = blockIdx.y * 256;
  if (m0 >= ne) return;
  int nb = blockIdx.x;

  __shared__ u16 al[2][256 * 64];   // A tile (2 half-tiles of 128x64)
  __shared__ u16 bl0[2][128 * 64];  // B group 0
  __shared__ u16 bl1[2][128 * 64];  // B group 1
  __shared__ int s_pair[256];
  __shared__ float s_w[256];

  int tid = threadIdx.x;
  if (tid < 256) {
    int idx = m0 + tid;
    int pr = list[e * T_TOKENS + (idx < ne ? idx : 0)];
    s_pair[tid] = pr;
    if (!G1) s_w[tid] = wpair[pr];
  }
  __syncthreads();

  int w = tid >> 6, lane = tid & 63;
  // staging geometry: half-tile = 128 rows x 64 cols (16 KB); thread does 2
  // 16B loads; source col XOR-swizzled by row&7 so linear LDS dest ends up
  // swizzled (rule #21).
  int L0 = w * 128 + lane;
  int r0 = L0 >> 3, r1 = r0 + 8;
  int sc0 = (((L0 & 7) ^ (r0 & 7)) << 3);
  int sc1 = (((L0 & 7) ^ (r1 & 7)) << 3);

  const u16* Ap[2][2];  // [half][p]
#pragma unroll
  for (int h = 0; h < 2; h++) {
    int tk0 = s_pair[r0 + 128 * h];
    int tk1 = s_pair[r1 + 128 * h];
    if (G1) { tk0 >>= 1; tk1 >>= 1; }
    Ap[h][0] = Asrc + (size_t)tk0 * K + sc0;
    Ap[h][1] = Asrc + (size_t)tk1 * K + sc1;
  }
  const u16* Bp[2][2];  // [group][p]
#pragma unroll
  for (int g = 0; g < 2; g++) {
    const u16* src = g ? B1src : B0src;
    size_t rowg = G1 ? (size_t)nb * 128 : ((size_t)nb * 256 + g * 128);
    Bp[g][0] = src + ((size_t)e * BR + rowg + r0) * K + sc0;
    Bp[g][1] = src + ((size_t)e * BR + rowg + r1) * K + sc1;
  }

  int wm = (w & 3) * 64, wn = (w >> 2) * 64;
  int fr = lane & 15, q0 = lane >> 4;

  f32x4 zero = {0.f, 0.f, 0.f, 0.f};
  f32x4 a0[4][4], a1[4][4];
#pragma unroll
  for (int i = 0; i < 4; i++)
#pragma unroll
    for (int j = 0; j < 4; j++) { a0[i][j] = zero; a1[i][j] = zero; }

  auto stageA = [&](int h, int b, int kt) {
    GLOAD_LDS(Ap[h][0] + kt, &al[b][h * 8192 + (w * 128 + lane) * 8]);
    GLOAD_LDS(Ap[h][1] + kt, &al[b][h * 8192 + (w * 128 + 64 + lane) * 8]);
  };
  auto stageB = [&](int g, int b, int kt) {
    u16* dst = g ? &bl1[b][0] : &bl0[b][0];
    GLOAD_LDS(Bp[g][0] + kt, dst + (w * 128 + lane) * 8);
    GLOAD_LDS(Bp[g][1] + kt, dst + (w * 128 + 64 + lane) * 8);
  };
  auto ldA = [&](bf16x8 (&af)[4], const u16* alc, int kk) {
#pragma unroll
    for (int i = 0; i < 4; i++) {
      int row = wm + i * 16 + fr;
      af[i] = *(const bf16x8*)&alc[row * 64 +
                                   (((kk * 4 + q0) ^ (row & 7)) << 3)];
    }
  };
  auto ldB = [&](bf16x8 (&bf)[4], const u16* blc, int kk) {
#pragma unroll
    for (int j = 0; j < 4; j++) {
      int row = wn + j * 16 + fr;
      bf[j] = *(const bf16x8*)&blc[row * 64 +
                                   (((kk * 4 + q0) ^ (row & 7)) << 3)];
    }
  };
  auto mm = [&](f32x4 (&acc)[4][4], bf16x8 (&af)[4], bf16x8 (&bf)[4]) {
    __builtin_amdgcn_s_setprio(1);
#pragma unroll
    for (int i = 0; i < 4; i++)
#pragma unroll
      for (int j = 0; j < 4; j++)
        acc[i][j] = __builtin_amdgcn_mfma_f32_16x16x32_bf16(af[i], bf[j],
                                                            acc[i][j], 0, 0, 0);
    __builtin_amdgcn_s_setprio(0);
    __builtin_amdgcn_sched_barrier(0);
  };

#define PHASE_SYNC()                                                           \
  __builtin_amdgcn_sched_barrier(0);                                           \
  __builtin_amdgcn_s_barrier();                                                \
  asm volatile("s_waitcnt lgkmcnt(0)" ::: "memory");                           \
  __builtin_amdgcn_sched_barrier(0)

#define GATE_VM2()                                                             \
  asm volatile("s_waitcnt vmcnt(2)" ::: "memory");                             \
  __builtin_amdgcn_s_barrier();                                                \
  asm volatile("" ::: "memory")

#define BAR_PLAIN()                                                            \
  __builtin_amdgcn_s_barrier();                                                \
  asm volatile("" ::: "memory")

  // prologue: stage tile 0 fully, drain, barrier
  stageA(0, 0, 0); stageA(1, 0, 0); stageB(0, 0, 0); stageB(1, 0, 0);
  asm volatile("s_waitcnt vmcnt(0)" ::: "memory");
  BAR_PLAIN();

  int cur = 0;
#pragma unroll 1
  for (int t = 0; t < NT; ++t) {
    const u16* alc = &al[cur][0];
    const u16* bl0c = &bl0[cur][0];
    const u16* bl1c = &bl1[cur][0];
    int nxt = cur ^ 1;
    int ktn = (t + 1) * 64;
    bool pf = (t + 1 < NT);

    bf16x8 af[4], bfr[4];
    // ---- Phase A: acc0 @ kk0; stage A-lo(t+1) ----
    ldA(af, alc, 0);
    ldB(bfr, bl0c, 0);
    if (pf) stageA(0, nxt, ktn);
    PHASE_SYNC();
    mm(a0, af, bfr);
    GATE_VM2();  // B1(t) landed collectively (outstanding: A-lo(t+1))
    // ---- Phase B: acc1 @ kk0; stage A-hi(t+1) ----
    ldB(bfr, bl1c, 0);
    if (pf) stageA(1, nxt, ktn);
    PHASE_SYNC();
    mm(a1, af, bfr);
    BAR_PLAIN();
    // ---- Phase C: acc0 @ kk1; stage B0(t+1) ----
    ldA(af, alc, 1);
    ldB(bfr, bl0c, 1);
    if (pf) stageB(0, nxt, ktn);
    PHASE_SYNC();
    mm(a0, af, bfr);
    BAR_PLAIN();
    // ---- Phase D: acc1 @ kk1; stage B1(t+1) ----
    ldB(bfr, bl1c, 1);
    if (pf) stageB(1, nxt, ktn);
    PHASE_SYNC();
    mm(a1, af, bfr);
    GATE_VM2();  // A-lo,A-hi,B0 of t+1 landed (outstanding: B1(t+1))
    cur = nxt;
  }

  // ---- epilogue ----
  if (G1) {
    // SwiGLU: silu(h1) * h3 -> inter (bf16), scattered rows by pair id
#pragma unroll
    for (int i = 0; i < 4; i++) {
#pragma unroll
      for (int r = 0; r < 4; r++) {
        int ml = wm + i * 16 + q0 * 4 + r;
        if (m0 + ml < ne) {
          size_t base = (size_t)s_pair[ml] * F_DIM + (size_t)nb * 128 + wn + fr;
#pragma unroll
          for (int j = 0; j < 4; j++) {
            float h1 = a0[i][j][r], h3 = a1[i][j][r];
            float v = h1 / (1.f + __expf(-h1)) * h3;
            inter[base + j * 16] = f2bf(v);
          }
        }
      }
    }
  } else {
    // scale by routing weight, atomicAdd into out (2 adds/elem, commutative)
#pragma unroll
    for (int i = 0; i < 4; i++) {
#pragma unroll
      for (int r = 0; r < 4; r++) {
        int ml = wm + i * 16 + q0 * 4 + r;
        if (m0 + ml < ne) {
          int pr = s_pair[ml];
          float wgt = s_w[ml];
          float* ob = out + (size_t)(pr >> 1) * H_DIM + (size_t)nb * 256 + wn + fr;
#pragma unroll
          for (int j = 0; j < 4; j++) {
            atomicAdd(ob + j * 16, a0[i][j][r] * wgt);
            atomicAdd(ob + 128 + j * 16, a1[i][j][r] * wgt);
          }
        }
      }
    }
  }
}

// ---------------- workspace layout (bytes) ----------------
#define XB_OFF 0UL
#define W1B_OFF (XB_OFF + (size_t)T_TOKENS * H_DIM * 2)
#define W3B_OFF (W1B_OFF + (size_t)E_NUM * F_DIM * H_DIM * 2)
#define W2B_OFF (W3B_OFF + (size_t)E_NUM * F_DIM * H_DIM * 2)
#define INTER_OFF (W2B_OFF + (size_t)E_NUM * F_DIM * H_DIM * 2)
#define CNT_OFF (INTER_OFF + (size_t)2 * T_TOKENS * F_DIM * 2)
#define LIST_OFF (CNT_OFF + 256)
#define WPAIR_OFF (LIST_OFF + (size_t)E_NUM * T_TOKENS * 4)
#define SEL_OFF (WPAIR_OFF + (size_t)2 * T_TOKENS * 4)
#define SELW_OFF (SEL_OFF + (size_t)2 * T_TOKENS * 4)

extern "C" void kernel_launch(void* const* d_in, const int* in_sizes, int n_in,
                              void* d_out, int out_size, void* d_ws,
                              size_t ws_size, hipStream_t stream) {
  const float* x = (const float*)d_in[0];
  const float* gw = (const float*)d_in[1];
  const float* w1 = (const float*)d_in[2];
  const float* w2 = (const float*)d_in[3];
  const float* w3 = (const float*)d_in[4];
  float* out = (float*)d_out;
  float* logits_out = out + (size_t)T_TOKENS * H_DIM;

  char* ws = (char*)d_ws;
  u16* xb = (u16*)(ws + XB_OFF);
  u16* w1b = (u16*)(ws + W1B_OFF);
  u16* w3b = (u16*)(ws + W3B_OFF);
  u16* w2b = (u16*)(ws + W2B_OFF);
  u16* inter = (u16*)(ws + INTER_OFF);
  int* cnt = (int*)(ws + CNT_OFF);
  int* list = (int*)(ws + LIST_OFF);
  float* wpair = (float*)(ws + WPAIR_OFF);
  int* sel = (int*)(ws + SEL_OFF);
  float* selw = (float*)(ws + SELW_OFF);

  hipMemsetAsync(d_out, 0, (size_t)T_TOKENS * H_DIM * sizeof(float), stream);
  hipMemsetAsync(cnt, 0, 256, stream);

  cvt_kernel<<<2048, 256, 0, stream>>>(w1, w1b, E_NUM * F_DIM * H_DIM / 4);
  cvt_kernel<<<2048, 256, 0, stream>>>(w3, w3b, E_NUM * F_DIM * H_DIM / 4);
  cvt_kernel<<<2048, 256, 0, stream>>>(w2, w2b, E_NUM * F_DIM * H_DIM / 4);

  router_kernel<<<T_TOKENS / 4, 256, 0, stream>>>(x, gw, xb, logits_out, sel,
                                                  selw);
  scatter_kernel<<<T_TOKENS / 256, 256, 0, stream>>>(sel, selw, cnt, list,
                                                     wpair);

  // GEMM1: 256 tokens x 128 F-cols (x2 groups: w1,w3 share cols)
  moe_gemm_kernel<true>
      <<<dim3(F_DIM / 128, T_TOKENS / 256, E_NUM), 512, 0, stream>>>(
          xb, w1b, w3b, cnt, list, wpair, inter, out);
  // GEMM2: 256 pairs x 256 H-cols (2 groups of 128)
  moe_gemm_kernel<false>
      <<<dim3(H_DIM / 256, T_TOKENS / 256, E_NUM), 512, 0, stream>>>(
          inter, w2b, w2b, cnt, list, wpair, inter, out);
}

// Round 4
// 743.528 us; speedup vs baseline: 1.2734x; 1.1000x over previous
//
#include <hip/hip_runtime.h>

// Problem constants (B=4, S=2048 -> T=8192)
#define T_TOKENS 8192
#define H_DIM 1024
#define F_DIM 4096
#define E_NUM 8

typedef unsigned short u16;
typedef __attribute__((ext_vector_type(8))) short bf16x8;
typedef __attribute__((ext_vector_type(4))) float f32x4;

__device__ __forceinline__ u16 f2bf(float f) {
  union { float f; unsigned int u; } v; v.f = f;
  unsigned int r = v.u + 0x7fffu + ((v.u >> 16) & 1u);
  return (u16)(r >> 16);
}
__device__ __forceinline__ float bf2f(u16 u) {
  union { unsigned int u; float f; } v; v.u = ((unsigned int)u) << 16;
  return v.f;
}

#define GLOAD_LDS(g, l)                                                        \
  __builtin_amdgcn_global_load_lds(                                            \
      (const __attribute__((address_space(1))) void*)(g),                      \
      (__attribute__((address_space(3))) void*)(l), 16, 0, 0)

// ---------------- fp32 -> bf16 convert (vectorized) ----------------
__global__ void cvt_kernel(const float* __restrict__ in, u16* __restrict__ out,
                           int n4) {
  int i = blockIdx.x * blockDim.x + threadIdx.x;
  int stride = gridDim.x * blockDim.x;
  for (; i < n4; i += stride) {
    float4 v = ((const float4*)in)[i];
    ushort4 o;
    o.x = f2bf(v.x); o.y = f2bf(v.y); o.z = f2bf(v.z); o.w = f2bf(v.w);
    ((ushort4*)out)[i] = o;
  }
}

// ------- router: logits + softmax + top2 + renorm, fused x->bf16 cvt -------
__global__ void router_kernel(const float* __restrict__ x,
                              const float* __restrict__ gw,
                              u16* __restrict__ xb,
                              float* __restrict__ logits_out,
                              int* __restrict__ sel, float* __restrict__ selw) {
  int wid = threadIdx.x >> 6;
  int lane = threadIdx.x & 63;
  int t = blockIdx.x * 4 + wid;
  const float4* xr = (const float4*)(x + (size_t)t * H_DIM);
  ushort4* xbr = (ushort4*)(xb + (size_t)t * H_DIM);
  float acc[E_NUM];
#pragma unroll
  for (int e = 0; e < E_NUM; e++) acc[e] = 0.f;
#pragma unroll
  for (int it = 0; it < H_DIM / 256; it++) {
    int i4 = it * 64 + lane;
    float4 v = xr[i4];
    ushort4 o;
    o.x = f2bf(v.x); o.y = f2bf(v.y); o.z = f2bf(v.z); o.w = f2bf(v.w);
    xbr[i4] = o;
#pragma unroll
    for (int e = 0; e < E_NUM; e++) {
      float4 g = ((const float4*)(gw + (size_t)e * H_DIM))[i4];
      acc[e] += v.x * g.x + v.y * g.y + v.z * g.z + v.w * g.w;
    }
  }
#pragma unroll
  for (int off = 32; off > 0; off >>= 1) {
#pragma unroll
    for (int e = 0; e < E_NUM; e++) acc[e] += __shfl_xor(acc[e], off);
  }
  if (lane < E_NUM) logits_out[(size_t)t * E_NUM + lane] = acc[lane];
  if (lane == 0) {
    float m = acc[0];
#pragma unroll
    for (int e = 1; e < E_NUM; e++) m = fmaxf(m, acc[e]);
    float p[E_NUM];
#pragma unroll
    for (int e = 0; e < E_NUM; e++) p[e] = expf(acc[e] - m);
    int e0 = 0; float p0 = p[0];
#pragma unroll
    for (int e = 1; e < E_NUM; e++) if (p[e] > p0) { p0 = p[e]; e0 = e; }
    int e1 = -1; float p1 = -1.f;
#pragma unroll
    for (int e = 0; e < E_NUM; e++)
      if (e != e0 && p[e] > p1) { p1 = p[e]; e1 = e; }
    float inv = 1.f / (p0 + p1);  // softmax denom cancels in renorm
    sel[t * 2] = e0; sel[t * 2 + 1] = e1;
    selw[t * 2] = p0 * inv; selw[t * 2 + 1] = p1 * inv;
  }
}

// ---------------- scatter: build per-expert pair lists ----------------
__global__ void scatter_kernel(const int* __restrict__ sel,
                               const float* __restrict__ selw,
                               int* __restrict__ cnt, int* __restrict__ list,
                               float* __restrict__ wpair) {
  int t = blockIdx.x * blockDim.x + threadIdx.x;
  if (t >= T_TOKENS) return;
#pragma unroll
  for (int k = 0; k < 2; k++) {
    int e = sel[t * 2 + k];
    int pos = atomicAdd(&cnt[e], 1);
    list[e * T_TOKENS + pos] = t * 2 + k;
    wpair[t * 2 + k] = selw[t * 2 + k];
  }
}

// ---- GEMM1: inter = silu(x@w1^T) * (x@w3^T), bf16 out ----
// 128x128 tile, BK=64, 4 waves of 4x4 16x16x32 fragments, XOR-swizzled LDS
// (swizzle applied on global source; linear global_load_lds dest — rule #21).
__global__ __launch_bounds__(256, 2) void gemm1_kernel(
    const u16* __restrict__ xb, const u16* __restrict__ w1b,
    const u16* __restrict__ w3b, const int* __restrict__ cnt,
    const int* __restrict__ list, u16* __restrict__ inter) {
  int e = blockIdx.z;
  int ne = cnt[e];
  int m0 = blockIdx.y * 128;
  if (m0 >= ne) return;
  int nb = blockIdx.x;

  __shared__ u16 al[128 * 64];
  __shared__ u16 b1l[128 * 64];
  __shared__ u16 b3l[128 * 64];
  __shared__ int s_pair[128];

  int tid = threadIdx.x;
  if (tid < 128) {
    int idx = m0 + tid;
    s_pair[tid] = list[e * T_TOKENS + (idx < ne ? idx : 0)];
  }
  __syncthreads();

  int sc = (((tid & 7) ^ ((tid >> 3) & 7)) << 3);
  const u16 *ab[4], *b1b[4], *b3b[4];
#pragma unroll
  for (int r = 0; r < 4; r++) {
    int row = r * 32 + (tid >> 3);
    ab[r] = xb + (size_t)(s_pair[row] >> 1) * H_DIM + sc;
    b1b[r] = w1b + ((size_t)e * F_DIM + (size_t)nb * 128 + row) * H_DIM + sc;
    b3b[r] = w3b + ((size_t)e * F_DIM + (size_t)nb * 128 + row) * H_DIM + sc;
  }

  int lane = tid & 63;
  int wm = ((tid >> 7) & 1) * 64;
  int wn = ((tid >> 6) & 1) * 64;
  f32x4 zero = {0.f, 0.f, 0.f, 0.f};
  f32x4 acc1[4][4], acc3[4][4];
#pragma unroll
  for (int i = 0; i < 4; i++)
#pragma unroll
    for (int j = 0; j < 4; j++) { acc1[i][j] = zero; acc3[i][j] = zero; }

  for (int kt = 0; kt < H_DIM; kt += 64) {
#pragma unroll
    for (int r = 0; r < 4; r++) {
      int c8 = (r * 256 + tid) * 8;
      GLOAD_LDS(ab[r] + kt, &al[c8]);
      GLOAD_LDS(b1b[r] + kt, &b1l[c8]);
      GLOAD_LDS(b3b[r] + kt, &b3l[c8]);
    }
    __syncthreads();
#pragma unroll
    for (int kk = 0; kk < 2; kk++) {
      int q = kk * 4 + (lane >> 4);
      bf16x8 af[4], bf1[4], bf3[4];
#pragma unroll
      for (int i = 0; i < 4; i++) {
        int row = wm + i * 16 + (lane & 15);
        af[i] = *(const bf16x8*)&al[row * 64 + ((q ^ (row & 7)) << 3)];
      }
#pragma unroll
      for (int j = 0; j < 4; j++) {
        int row = wn + j * 16 + (lane & 15);
        int off = row * 64 + ((q ^ (row & 7)) << 3);
        bf1[j] = *(const bf16x8*)&b1l[off];
        bf3[j] = *(const bf16x8*)&b3l[off];
      }
#pragma unroll
      for (int i = 0; i < 4; i++)
#pragma unroll
        for (int j = 0; j < 4; j++) {
          acc1[i][j] = __builtin_amdgcn_mfma_f32_16x16x32_bf16(
              af[i], bf1[j], acc1[i][j], 0, 0, 0);
          acc3[i][j] = __builtin_amdgcn_mfma_f32_16x16x32_bf16(
              af[i], bf3[j], acc3[i][j], 0, 0, 0);
        }
    }
    __syncthreads();
  }

#pragma unroll
  for (int i = 0; i < 4; i++) {
#pragma unroll
    for (int r = 0; r < 4; r++) {
      int ml = wm + i * 16 + (lane >> 4) * 4 + r;
      if (m0 + ml < ne) {
        size_t base =
            (size_t)s_pair[ml] * F_DIM + (size_t)nb * 128 + wn + (lane & 15);
#pragma unroll
        for (int j = 0; j < 4; j++) {
          float h1 = acc1[i][j][r], h3 = acc3[i][j][r];
          float v = h1 / (1.f + __expf(-h1)) * h3;
          inter[base + j * 16] = f2bf(v);
        }
      }
    }
  }
}

// ---- GEMM2: y[pair] = inter[pair] @ w2^T  (plain bf16 stores, no atomics) --
__global__ __launch_bounds__(256, 2) void gemm2_kernel(
    const u16* __restrict__ inter, const u16* __restrict__ w2b,
    const int* __restrict__ cnt, const int* __restrict__ list,
    u16* __restrict__ y) {
  int e = blockIdx.z;
  int ne = cnt[e];
  int m0 = blockIdx.y * 128;
  if (m0 >= ne) return;
  int nb = blockIdx.x;  // H / 128

  __shared__ u16 al[128 * 64];
  __shared__ u16 bl[128 * 64];
  __shared__ int s_pair[128];

  int tid = threadIdx.x;
  if (tid < 128) {
    int idx = m0 + tid;
    s_pair[tid] = list[e * T_TOKENS + (idx < ne ? idx : 0)];
  }
  __syncthreads();

  int sc = (((tid & 7) ^ ((tid >> 3) & 7)) << 3);
  const u16 *ab[4], *bb[4];
#pragma unroll
  for (int r = 0; r < 4; r++) {
    int row = r * 32 + (tid >> 3);
    ab[r] = inter + (size_t)s_pair[row] * F_DIM + sc;
    bb[r] = w2b + ((size_t)e * H_DIM + (size_t)nb * 128 + row) * F_DIM + sc;
  }

  int lane = tid & 63;
  int wm = ((tid >> 7) & 1) * 64;
  int wn = ((tid >> 6) & 1) * 64;
  f32x4 zero = {0.f, 0.f, 0.f, 0.f};
  f32x4 acc[4][4];
#pragma unroll
  for (int i = 0; i < 4; i++)
#pragma unroll
    for (int j = 0; j < 4; j++) acc[i][j] = zero;

  for (int kt = 0; kt < F_DIM; kt += 64) {
#pragma unroll
    for (int r = 0; r < 4; r++) {
      int c8 = (r * 256 + tid) * 8;
      GLOAD_LDS(ab[r] + kt, &al[c8]);
      GLOAD_LDS(bb[r] + kt, &bl[c8]);
    }
    __syncthreads();
#pragma unroll
    for (int kk = 0; kk < 2; kk++) {
      int q = kk * 4 + (lane >> 4);
      bf16x8 af[4], bf[4];
#pragma unroll
      for (int i = 0; i < 4; i++) {
        int row = wm + i * 16 + (lane & 15);
        af[i] = *(const bf16x8*)&al[row * 64 + ((q ^ (row & 7)) << 3)];
      }
#pragma unroll
      for (int j = 0; j < 4; j++) {
        int row = wn + j * 16 + (lane & 15);
        bf[j] = *(const bf16x8*)&bl[row * 64 + ((q ^ (row & 7)) << 3)];
      }
#pragma unroll
      for (int i = 0; i < 4; i++)
#pragma unroll
        for (int j = 0; j < 4; j++)
          acc[i][j] = __builtin_amdgcn_mfma_f32_16x16x32_bf16(
              af[i], bf[j], acc[i][j], 0, 0, 0);
    }
    __syncthreads();
  }

  // epilogue: plain bf16 stores into pair-indexed buffer (each pair row is
  // written by exactly one block -> no atomics needed)
#pragma unroll
  for (int i = 0; i < 4; i++) {
#pragma unroll
    for (int r = 0; r < 4; r++) {
      int ml = wm + i * 16 + (lane >> 4) * 4 + r;
      if (m0 + ml < ne) {
        u16* yb =
            y + (size_t)s_pair[ml] * H_DIM + (size_t)nb * 128 + wn + (lane & 15);
#pragma unroll
        for (int j = 0; j < 4; j++) yb[j * 16] = f2bf(acc[i][j][r]);
      }
    }
  }
}

// ---- combine: out[t] = w0 * y[2t] + w1 * y[2t+1] (fp32 out) ----
__global__ void combine_kernel(const u16* __restrict__ y,
                               const float* __restrict__ wpair,
                               float* __restrict__ out) {
  int t = blockIdx.x;
  float w0 = wpair[t * 2], w1 = wpair[t * 2 + 1];
  const ushort4* y0 = (const ushort4*)(y + (size_t)t * 2 * H_DIM);
  const ushort4* y1 = (const ushort4*)(y + ((size_t)t * 2 + 1) * H_DIM);
  float4* o = (float4*)(out + (size_t)t * H_DIM);
  int i = threadIdx.x;  // 256 threads x 4 elems = 1024 = H_DIM
  ushort4 a = y0[i], b = y1[i];
  float4 r;
  r.x = w0 * bf2f(a.x) + w1 * bf2f(b.x);
  r.y = w0 * bf2f(a.y) + w1 * bf2f(b.y);
  r.z = w0 * bf2f(a.z) + w1 * bf2f(b.z);
  r.w = w0 * bf2f(a.w) + w1 * bf2f(b.w);
  o[i] = r;
}

// ---------------- workspace layout (bytes) ----------------
#define XB_OFF 0UL
#define W1B_OFF (XB_OFF + (size_t)T_TOKENS * H_DIM * 2)
#define W3B_OFF (W1B_OFF + (size_t)E_NUM * F_DIM * H_DIM * 2)
#define W2B_OFF (W3B_OFF + (size_t)E_NUM * F_DIM * H_DIM * 2)
#define INTER_OFF (W2B_OFF + (size_t)E_NUM * F_DIM * H_DIM * 2)
#define CNT_OFF (INTER_OFF + (size_t)2 * T_TOKENS * F_DIM * 2)
#define LIST_OFF (CNT_OFF + 256)
#define WPAIR_OFF (LIST_OFF + (size_t)E_NUM * T_TOKENS * 4)
#define SEL_OFF (WPAIR_OFF + (size_t)2 * T_TOKENS * 4)
#define SELW_OFF (SEL_OFF + (size_t)2 * T_TOKENS * 4)
// y (2T x H bf16, 32 MiB) aliases the w1b region: w1b is dead once gemm1 has
// run; gemm2 writes y afterwards; next call's cvt(w1) rewrites it. All
// stream-ordered -> deterministic.
#define Y_OFF W1B_OFF

extern "C" void kernel_launch(void* const* d_in, const int* in_sizes, int n_in,
                              void* d_out, int out_size, void* d_ws,
                              size_t ws_size, hipStream_t stream) {
  const float* x = (const float*)d_in[0];
  const float* gw = (const float*)d_in[1];
  const float* w1 = (const float*)d_in[2];
  const float* w2 = (const float*)d_in[3];
  const float* w3 = (const float*)d_in[4];
  float* out = (float*)d_out;
  float* logits_out = out + (size_t)T_TOKENS * H_DIM;

  char* ws = (char*)d_ws;
  u16* xb = (u16*)(ws + XB_OFF);
  u16* w1b = (u16*)(ws + W1B_OFF);
  u16* w3b = (u16*)(ws + W3B_OFF);
  u16* w2b = (u16*)(ws + W2B_OFF);
  u16* inter = (u16*)(ws + INTER_OFF);
  u16* y = (u16*)(ws + Y_OFF);
  int* cnt = (int*)(ws + CNT_OFF);
  int* list = (int*)(ws + LIST_OFF);
  float* wpair = (float*)(ws + WPAIR_OFF);
  int* sel = (int*)(ws + SEL_OFF);
  float* selw = (float*)(ws + SELW_OFF);

  hipMemsetAsync(cnt, 0, 256, stream);

  cvt_kernel<<<2048, 256, 0, stream>>>(w1, w1b, E_NUM * F_DIM * H_DIM / 4);
  cvt_kernel<<<2048, 256, 0, stream>>>(w3, w3b, E_NUM * F_DIM * H_DIM / 4);
  cvt_kernel<<<2048, 256, 0, stream>>>(w2, w2b, E_NUM * F_DIM * H_DIM / 4);

  router_kernel<<<T_TOKENS / 4, 256, 0, stream>>>(x, gw, xb, logits_out, sel,
                                                  selw);
  scatter_kernel<<<T_TOKENS / 256, 256, 0, stream>>>(sel, selw, cnt, list,
                                                     wpair);

  gemm1_kernel<<<dim3(F_DIM / 128, T_TOKENS / 128, E_NUM), 256, 0, stream>>>(
      xb, w1b, w3b, cnt, list, inter);
  gemm2_kernel<<<dim3(H_DIM / 128, T_TOKENS / 128, E_NUM), 256, 0, stream>>>(
      inter, w2b, cnt, list, y);
  combine_kernel<<<T_TOKENS, 256, 0, stream>>>(y, wpair, out);
}

// Round 5
// 741.791 us; speedup vs baseline: 1.2764x; 1.0023x over previous
//
#include <hip/hip_runtime.h>

// Problem constants (B=4, S=2048 -> T=8192)
#define T_TOKENS 8192
#define H_DIM 1024
#define F_DIM 4096
#define E_NUM 8

typedef unsigned short u16;
typedef __attribute__((ext_vector_type(8))) short bf16x8;
typedef __attribute__((ext_vector_type(4))) float f32x4;

__device__ __forceinline__ u16 f2bf(float f) {
  union { float f; unsigned int u; } v; v.f = f;
  unsigned int r = v.u + 0x7fffu + ((v.u >> 16) & 1u);
  return (u16)(r >> 16);
}
__device__ __forceinline__ float bf2f(u16 u) {
  union { unsigned int u; float f; } v; v.u = ((unsigned int)u) << 16;
  return v.f;
}

#define GLOAD_LDS(g, l)                                                        \
  __builtin_amdgcn_global_load_lds(                                            \
      (const __attribute__((address_space(1))) void*)(g),                      \
      (__attribute__((address_space(3))) void*)(l), 16, 0, 0)

// ---------------- fp32 -> bf16 convert (vectorized) ----------------
__global__ void cvt_kernel(const float* __restrict__ in, u16* __restrict__ out,
                           int n4) {
  int i = blockIdx.x * blockDim.x + threadIdx.x;
  int stride = gridDim.x * blockDim.x;
  for (; i < n4; i += stride) {
    float4 v = ((const float4*)in)[i];
    ushort4 o;
    o.x = f2bf(v.x); o.y = f2bf(v.y); o.z = f2bf(v.z); o.w = f2bf(v.w);
    ((ushort4*)out)[i] = o;
  }
}

// ------- router: logits + softmax + top2 + renorm, fused x->bf16 cvt -------
__global__ void router_kernel(const float* __restrict__ x,
                              const float* __restrict__ gw,
                              u16* __restrict__ xb,
                              float* __restrict__ logits_out,
                              int* __restrict__ sel, float* __restrict__ selw) {
  int wid = threadIdx.x >> 6;
  int lane = threadIdx.x & 63;
  int t = blockIdx.x * 4 + wid;
  const float4* xr = (const float4*)(x + (size_t)t * H_DIM);
  ushort4* xbr = (ushort4*)(xb + (size_t)t * H_DIM);
  float acc[E_NUM];
#pragma unroll
  for (int e = 0; e < E_NUM; e++) acc[e] = 0.f;
#pragma unroll
  for (int it = 0; it < H_DIM / 256; it++) {
    int i4 = it * 64 + lane;
    float4 v = xr[i4];
    ushort4 o;
    o.x = f2bf(v.x); o.y = f2bf(v.y); o.z = f2bf(v.z); o.w = f2bf(v.w);
    xbr[i4] = o;
#pragma unroll
    for (int e = 0; e < E_NUM; e++) {
      float4 g = ((const float4*)(gw + (size_t)e * H_DIM))[i4];
      acc[e] += v.x * g.x + v.y * g.y + v.z * g.z + v.w * g.w;
    }
  }
#pragma unroll
  for (int off = 32; off > 0; off >>= 1) {
#pragma unroll
    for (int e = 0; e < E_NUM; e++) acc[e] += __shfl_xor(acc[e], off);
  }
  if (lane < E_NUM) logits_out[(size_t)t * E_NUM + lane] = acc[lane];
  if (lane == 0) {
    float m = acc[0];
#pragma unroll
    for (int e = 1; e < E_NUM; e++) m = fmaxf(m, acc[e]);
    float p[E_NUM];
#pragma unroll
    for (int e = 0; e < E_NUM; e++) p[e] = expf(acc[e] - m);
    int e0 = 0; float p0 = p[0];
#pragma unroll
    for (int e = 1; e < E_NUM; e++) if (p[e] > p0) { p0 = p[e]; e0 = e; }
    int e1 = -1; float p1 = -1.f;
#pragma unroll
    for (int e = 0; e < E_NUM; e++)
      if (e != e0 && p[e] > p1) { p1 = p[e]; e1 = e; }
    float inv = 1.f / (p0 + p1);  // softmax denom cancels in renorm
    sel[t * 2] = e0; sel[t * 2 + 1] = e1;
    selw[t * 2] = p0 * inv; selw[t * 2 + 1] = p1 * inv;
  }
}

// ---------------- scatter: build per-expert pair lists ----------------
__global__ void scatter_kernel(const int* __restrict__ sel,
                               const float* __restrict__ selw,
                               int* __restrict__ cnt, int* __restrict__ list,
                               float* __restrict__ wpair) {
  int t = blockIdx.x * blockDim.x + threadIdx.x;
  if (t >= T_TOKENS) return;
#pragma unroll
  for (int k = 0; k < 2; k++) {
    int e = sel[t * 2 + k];
    int pos = atomicAdd(&cnt[e], 1);
    list[e * T_TOKENS + pos] = t * 2 + k;
    wpair[t * 2 + k] = selw[t * 2 + k];
  }
}

// ---------------- exclusive scan of expert counts (8 values) ----------------
__global__ void scan_kernel(const int* __restrict__ cnt, int* __restrict__ base) {
  if (threadIdx.x == 0) {
    int b = 0;
#pragma unroll
    for (int e = 0; e < E_NUM; e++) { base[e] = b; b += cnt[e]; }
  }
}

// ---- GEMM1: inter[base[e]+pos] = silu(x@w1^T) * (x@w3^T), bf16, compacted --
// 128x128 tile, BK=64, 4 waves of 4x4 16x16x32 fragments, XOR-swizzled LDS
// (swizzle applied on global source; linear global_load_lds dest — rule #21).
__global__ __launch_bounds__(256, 2) void gemm1_kernel(
    const u16* __restrict__ xb, const u16* __restrict__ w1b,
    const u16* __restrict__ w3b, const int* __restrict__ cnt,
    const int* __restrict__ base, const int* __restrict__ list,
    u16* __restrict__ inter) {
  int e = blockIdx.z;
  int ne = cnt[e];
  int m0 = blockIdx.y * 128;
  if (m0 >= ne) return;
  int nb = blockIdx.x;
  int cbase = base[e];

  __shared__ u16 al[128 * 64];
  __shared__ u16 b1l[128 * 64];
  __shared__ u16 b3l[128 * 64];
  __shared__ int s_pair[128];

  int tid = threadIdx.x;
  if (tid < 128) {
    int idx = m0 + tid;
    s_pair[tid] = list[e * T_TOKENS + (idx < ne ? idx : 0)];
  }
  __syncthreads();

  int sc = (((tid & 7) ^ ((tid >> 3) & 7)) << 3);
  const u16 *ab[4], *b1b[4], *b3b[4];
#pragma unroll
  for (int r = 0; r < 4; r++) {
    int row = r * 32 + (tid >> 3);
    ab[r] = xb + (size_t)(s_pair[row] >> 1) * H_DIM + sc;
    b1b[r] = w1b + ((size_t)e * F_DIM + (size_t)nb * 128 + row) * H_DIM + sc;
    b3b[r] = w3b + ((size_t)e * F_DIM + (size_t)nb * 128 + row) * H_DIM + sc;
  }

  int lane = tid & 63;
  int wm = ((tid >> 7) & 1) * 64;
  int wn = ((tid >> 6) & 1) * 64;
  f32x4 zero = {0.f, 0.f, 0.f, 0.f};
  f32x4 acc1[4][4], acc3[4][4];
#pragma unroll
  for (int i = 0; i < 4; i++)
#pragma unroll
    for (int j = 0; j < 4; j++) { acc1[i][j] = zero; acc3[i][j] = zero; }

  for (int kt = 0; kt < H_DIM; kt += 64) {
#pragma unroll
    for (int r = 0; r < 4; r++) {
      int c8 = (r * 256 + tid) * 8;
      GLOAD_LDS(ab[r] + kt, &al[c8]);
      GLOAD_LDS(b1b[r] + kt, &b1l[c8]);
      GLOAD_LDS(b3b[r] + kt, &b3l[c8]);
    }
    __syncthreads();
#pragma unroll
    for (int kk = 0; kk < 2; kk++) {
      int q = kk * 4 + (lane >> 4);
      bf16x8 af[4], bf1[4], bf3[4];
#pragma unroll
      for (int i = 0; i < 4; i++) {
        int row = wm + i * 16 + (lane & 15);
        af[i] = *(const bf16x8*)&al[row * 64 + ((q ^ (row & 7)) << 3)];
      }
#pragma unroll
      for (int j = 0; j < 4; j++) {
        int row = wn + j * 16 + (lane & 15);
        int off = row * 64 + ((q ^ (row & 7)) << 3);
        bf1[j] = *(const bf16x8*)&b1l[off];
        bf3[j] = *(const bf16x8*)&b3l[off];
      }
#pragma unroll
      for (int i = 0; i < 4; i++)
#pragma unroll
        for (int j = 0; j < 4; j++) {
          acc1[i][j] = __builtin_amdgcn_mfma_f32_16x16x32_bf16(
              af[i], bf1[j], acc1[i][j], 0, 0, 0);
          acc3[i][j] = __builtin_amdgcn_mfma_f32_16x16x32_bf16(
              af[i], bf3[j], acc3[i][j], 0, 0, 0);
        }
    }
    __syncthreads();
  }

  // epilogue: SwiGLU, write compacted inter row (base[e] + list position)
#pragma unroll
  for (int i = 0; i < 4; i++) {
#pragma unroll
    for (int r = 0; r < 4; r++) {
      int ml = wm + i * 16 + (lane >> 4) * 4 + r;
      if (m0 + ml < ne) {
        size_t basei = (size_t)(cbase + m0 + ml) * F_DIM + (size_t)nb * 128 +
                       wn + (lane & 15);
#pragma unroll
        for (int j = 0; j < 4; j++) {
          float h1 = acc1[i][j][r], h3 = acc3[i][j][r];
          float v = h1 / (1.f + __expf(-h1)) * h3;
          inter[basei + j * 16] = f2bf(v);
        }
      }
    }
  }
}

// ---- GEMM2: y[pair] = inter[compact] @ w2^T  (plain bf16 stores) ----
// A rows are expert-contiguous (base[e]+idx) -> streaming reads, L2-friendly.
__global__ __launch_bounds__(256, 2) void gemm2_kernel(
    const u16* __restrict__ inter, const u16* __restrict__ w2b,
    const int* __restrict__ cnt, const int* __restrict__ base,
    const int* __restrict__ list, u16* __restrict__ y) {
  int e = blockIdx.z;
  int ne = cnt[e];
  int m0 = blockIdx.y * 128;
  if (m0 >= ne) return;
  int nb = blockIdx.x;  // H / 128
  int cbase = base[e];

  __shared__ u16 al[128 * 64];
  __shared__ u16 bl[128 * 64];
  __shared__ int s_pair[128];

  int tid = threadIdx.x;
  if (tid < 128) {
    int idx = m0 + tid;
    s_pair[tid] = list[e * T_TOKENS + (idx < ne ? idx : 0)];
  }
  __syncthreads();

  int sc = (((tid & 7) ^ ((tid >> 3) & 7)) << 3);
  const u16 *ab[4], *bb[4];
#pragma unroll
  for (int r = 0; r < 4; r++) {
    int row = r * 32 + (tid >> 3);
    int cr = m0 + row;
    if (cr >= ne) cr = 0;  // clamp within expert (guarded store anyway)
    ab[r] = inter + (size_t)(cbase + cr) * F_DIM + sc;
    bb[r] = w2b + ((size_t)e * H_DIM + (size_t)nb * 128 + row) * F_DIM + sc;
  }

  int lane = tid & 63;
  int wm = ((tid >> 7) & 1) * 64;
  int wn = ((tid >> 6) & 1) * 64;
  f32x4 zero = {0.f, 0.f, 0.f, 0.f};
  f32x4 acc[4][4];
#pragma unroll
  for (int i = 0; i < 4; i++)
#pragma unroll
    for (int j = 0; j < 4; j++) acc[i][j] = zero;

  for (int kt = 0; kt < F_DIM; kt += 64) {
#pragma unroll
    for (int r = 0; r < 4; r++) {
      int c8 = (r * 256 + tid) * 8;
      GLOAD_LDS(ab[r] + kt, &al[c8]);
      GLOAD_LDS(bb[r] + kt, &bl[c8]);
    }
    __syncthreads();
#pragma unroll
    for (int kk = 0; kk < 2; kk++) {
      int q = kk * 4 + (lane >> 4);
      bf16x8 af[4], bf[4];
#pragma unroll
      for (int i = 0; i < 4; i++) {
        int row = wm + i * 16 + (lane & 15);
        af[i] = *(const bf16x8*)&al[row * 64 + ((q ^ (row & 7)) << 3)];
      }
#pragma unroll
      for (int j = 0; j < 4; j++) {
        int row = wn + j * 16 + (lane & 15);
        bf[j] = *(const bf16x8*)&bl[row * 64 + ((q ^ (row & 7)) << 3)];
      }
#pragma unroll
      for (int i = 0; i < 4; i++)
#pragma unroll
        for (int j = 0; j < 4; j++)
          acc[i][j] = __builtin_amdgcn_mfma_f32_16x16x32_bf16(
              af[i], bf[j], acc[i][j], 0, 0, 0);
    }
    __syncthreads();
  }

  // epilogue: plain bf16 stores into pair-indexed y (one writer per row)
#pragma unroll
  for (int i = 0; i < 4; i++) {
#pragma unroll
    for (int r = 0; r < 4; r++) {
      int ml = wm + i * 16 + (lane >> 4) * 4 + r;
      if (m0 + ml < ne) {
        u16* yb =
            y + (size_t)s_pair[ml] * H_DIM + (size_t)nb * 128 + wn + (lane & 15);
#pragma unroll
        for (int j = 0; j < 4; j++) yb[j * 16] = f2bf(acc[i][j][r]);
      }
    }
  }
}

// ---- combine: out[t] = w0 * y[2t] + w1 * y[2t+1] (fp32 out) ----
__global__ void combine_kernel(const u16* __restrict__ y,
                               const float* __restrict__ wpair,
                               float* __restrict__ out) {
  int t = blockIdx.x;
  float w0 = wpair[t * 2], w1 = wpair[t * 2 + 1];
  const ushort4* y0 = (const ushort4*)(y + (size_t)t * 2 * H_DIM);
  const ushort4* y1 = (const ushort4*)(y + ((size_t)t * 2 + 1) * H_DIM);
  float4* o = (float4*)(out + (size_t)t * H_DIM);
  int i = threadIdx.x;  // 256 threads x 4 elems = 1024 = H_DIM
  ushort4 a = y0[i], b = y1[i];
  float4 r;
  r.x = w0 * bf2f(a.x) + w1 * bf2f(b.x);
  r.y = w0 * bf2f(a.y) + w1 * bf2f(b.y);
  r.z = w0 * bf2f(a.z) + w1 * bf2f(b.z);
  r.w = w0 * bf2f(a.w) + w1 * bf2f(b.w);
  o[i] = r;
}

// ---------------- workspace layout (bytes) ----------------
#define XB_OFF 0UL
#define W1B_OFF (XB_OFF + (size_t)T_TOKENS * H_DIM * 2)
#define W3B_OFF (W1B_OFF + (size_t)E_NUM * F_DIM * H_DIM * 2)
#define W2B_OFF (W3B_OFF + (size_t)E_NUM * F_DIM * H_DIM * 2)
#define INTER_OFF (W2B_OFF + (size_t)E_NUM * F_DIM * H_DIM * 2)
#define CNT_OFF (INTER_OFF + (size_t)2 * T_TOKENS * F_DIM * 2)
#define BASE_OFF (CNT_OFF + 64)
#define LIST_OFF (BASE_OFF + 192)
#define WPAIR_OFF (LIST_OFF + (size_t)E_NUM * T_TOKENS * 4)
#define SEL_OFF (WPAIR_OFF + (size_t)2 * T_TOKENS * 4)
#define SELW_OFF (SEL_OFF + (size_t)2 * T_TOKENS * 4)
// y (2T x H bf16, 32 MiB) aliases the w1b region: w1b is dead once gemm1 has
// run; gemm2 writes y afterwards; next call's cvt(w1) rewrites it. All
// stream-ordered -> deterministic.
#define Y_OFF W1B_OFF

extern "C" void kernel_launch(void* const* d_in, const int* in_sizes, int n_in,
                              void* d_out, int out_size, void* d_ws,
                              size_t ws_size, hipStream_t stream) {
  const float* x = (const float*)d_in[0];
  const float* gw = (const float*)d_in[1];
  const float* w1 = (const float*)d_in[2];
  const float* w2 = (const float*)d_in[3];
  const float* w3 = (const float*)d_in[4];
  float* out = (float*)d_out;
  float* logits_out = out + (size_t)T_TOKENS * H_DIM;

  char* ws = (char*)d_ws;
  u16* xb = (u16*)(ws + XB_OFF);
  u16* w1b = (u16*)(ws + W1B_OFF);
  u16* w3b = (u16*)(ws + W3B_OFF);
  u16* w2b = (u16*)(ws + W2B_OFF);
  u16* inter = (u16*)(ws + INTER_OFF);
  u16* y = (u16*)(ws + Y_OFF);
  int* cnt = (int*)(ws + CNT_OFF);
  int* base = (int*)(ws + BASE_OFF);
  int* list = (int*)(ws + LIST_OFF);
  float* wpair = (float*)(ws + WPAIR_OFF);
  int* sel = (int*)(ws + SEL_OFF);
  float* selw = (float*)(ws + SELW_OFF);

  hipMemsetAsync(cnt, 0, 64, stream);

  cvt_kernel<<<2048, 256, 0, stream>>>(w1, w1b, E_NUM * F_DIM * H_DIM / 4);
  cvt_kernel<<<2048, 256, 0, stream>>>(w3, w3b, E_NUM * F_DIM * H_DIM / 4);
  cvt_kernel<<<2048, 256, 0, stream>>>(w2, w2b, E_NUM * F_DIM * H_DIM / 4);

  router_kernel<<<T_TOKENS / 4, 256, 0, stream>>>(x, gw, xb, logits_out, sel,
                                                  selw);
  scatter_kernel<<<T_TOKENS / 256, 256, 0, stream>>>(sel, selw, cnt, list,
                                                     wpair);
  scan_kernel<<<1, 64, 0, stream>>>(cnt, base);

  gemm1_kernel<<<dim3(F_DIM / 128, T_TOKENS / 128, E_NUM), 256, 0, stream>>>(
      xb, w1b, w3b, cnt, base, list, inter);
  gemm2_kernel<<<dim3(H_DIM / 128, T_TOKENS / 128, E_NUM), 256, 0, stream>>>(
      inter, w2b, cnt, base, list, y);
  combine_kernel<<<T_TOKENS, 256, 0, stream>>>(y, wpair, out);
}